// Round 14
// baseline (82.268 us; speedup 1.0000x reference)
//
#include <hip/hip_runtime.h>

// ============================================================================
// DIAGNOSTIC ROUND: r11 kernel (best, 23.0 us) with device-side rep loops
// (k1 x8, k2 x4) so each dispatch exceeds the ~39-40 us harness fill dispatches
// and finally appears in rocprof top-5 with real counters. Reps are idempotent
// (same stores each rep); barriers at body boundaries keep reps race-free.
// True per-kernel time = dispatch_dur / rep.
// ============================================================================

#define NN 1024
#define K1_REP 8
#define K2_REP 4

typedef __attribute__((ext_vector_type(8))) short short8;
typedef __attribute__((ext_vector_type(4))) float floatx4;
typedef __attribute__((ext_vector_type(4))) unsigned int uint4v;
typedef _Float16 half2v __attribute__((ext_vector_type(2)));

// ---- ws layout (bytes) ----
#define R2_OFF   0u          // u32 R2[128][1024]: pk-f16 (R~_{2hp}, R~_{2hp+1}) per i
#define CT_OFF   524288u     // u32 Ct[32][1024][4]: pk-f16 Cn pairs, [hpg][j][hp&3]

__device__ __forceinline__ unsigned short f2bf(float x) {  // RNE f32->bf16
  unsigned u = __float_as_uint(x);
  return (unsigned short)((u + 0x7FFFu + ((u >> 16) & 1u)) >> 16);
}

__device__ __forceinline__ unsigned int pkf16(float a, float b) {
  unsigned int lo = (unsigned int)__builtin_bit_cast(unsigned short, (_Float16)a);
  unsigned int hi = (unsigned int)__builtin_bit_cast(unsigned short, (_Float16)b);
  return lo | (hi << 16);
}

__device__ __forceinline__ void dot2acc(unsigned int a, unsigned int b, float& acc) {
#if __has_builtin(__builtin_amdgcn_fdot2)
  acc = __builtin_amdgcn_fdot2(__builtin_bit_cast(half2v, a),
                               __builtin_bit_cast(half2v, b), acc, false);
#else
  asm("v_dot2_f32_f16 %0, %1, %2, %0" : "+v"(acc) : "v"(a), "v"(b));
#endif
}

// core: acc += dot2( pk_max(r, c), mul )
__device__ __forceinline__ void pkmaxdot(unsigned int r, unsigned int c,
                                         unsigned int mul, float& acc) {
  unsigned int m;
  asm("v_pk_max_f16 %0, %1, %2" : "=v"(m) : "v"(r), "v"(c));
  dot2acc(m, mul, acc);
}

// ---------------- k1: fused prep + fc1 GEMM (bf16 MFMA) -> pk-f16 R2 / Ct ----------------
__global__ __launch_bounds__(256) void k1_fused(const float* __restrict__ z,
    const float* __restrict__ W1, const float* __restrict__ b1,
    const float* __restrict__ W2, char* __restrict__ ws) {
  __shared__ unsigned short zsh[16][272];      // 8.7 KB
  __shared__ unsigned short wsh[4][16][272];   // 34.8 KB
  __shared__ float tile[4][16][17];            // 4.4 KB
  unsigned int* R2 = (unsigned int*)(ws + R2_OFF);
  unsigned int* Ct = (unsigned int*)(ws + CT_OFF);

  const int t = threadIdx.x;
  const int l = t & 63, w = t >> 6;
  const int i0 = blockIdx.x * 16;
  const int tid = blockIdx.y * 4 + w;          // q-tile id 0..31
  const int q0 = tid * 16;                     // 0..496
  const bool topR = q0 < 256;
  const int h0 = q0 & 255;
  const int off = topR ? 0 : 256;

  #pragma unroll 1
  for (int rep = 0; rep < K1_REP; ++rep) {     // DIAGNOSTIC rep
    // stage z i-tile: 1024 float4, 4 per thread, coalesced; convert to bf16
    #pragma unroll
    for (int k = 0; k < 4; ++k) {
      const int f = t + k * 256;               // float4 index 0..1023
      const int r = f >> 6, c4 = f & 63;
      const float4 v = *(const float4*)(z + (i0 + r) * 256 + c4 * 4);
      ushort4 u;
      u.x = f2bf(v.x); u.y = f2bf(v.y); u.z = f2bf(v.z); u.w = f2bf(v.w);
      *(ushort4*)&zsh[r][c4 * 4] = u;
    }
    // stage W1 q-slice (per wave)
    #pragma unroll 4
    for (int r = 0; r < 16; ++r) {
      const int h = h0 + r;
      const float wa = fabsf(W2[h]);
      const float sc = topR ? wa : -wa;
      const float4 v = *(const float4*)(W1 + h * 512 + off + l * 4);
      ushort4 u;
      u.x = f2bf(v.x * sc); u.y = f2bf(v.y * sc);
      u.z = f2bf(v.z * sc); u.w = f2bf(v.w * sc);
      *(ushort4*)&wsh[w][r][l * 4] = u;
    }
    __syncthreads();

    floatx4 acc = {0.f, 0.f, 0.f, 0.f};
    const int fr = l & 15, fg = (l >> 4) * 8;
    #pragma unroll
    for (int kk = 0; kk < 8; ++kk) {
      const short8 a  = *(const short8*)&zsh[fr][fg + kk * 32];
      const short8 bb = *(const short8*)&wsh[w][fr][fg + kk * 32];
      acc = __builtin_amdgcn_mfma_f32_16x16x32_bf16(a, bb, acc, 0, 0, 0);
    }

    const int col = l & 15, r0 = (l >> 4) * 4;
    float bias = 0.f;
    if (topR) {
      const int h = q0 + col;
      bias = b1[h] * fabsf(W2[h]);
    }
    #pragma unroll
    for (int q = 0; q < 4; ++q) tile[w][r0 + q][col] = acc[q] + bias;
    __syncthreads();
    const int il = l & 15, g2 = l >> 4;
    if (topR) {
      #pragma unroll
      for (int e = 0; e < 2; ++e) {
        const int qc = g2 * 4 + e * 2;
        const unsigned int pk = pkf16(tile[w][il][qc], tile[w][il][qc + 1]);
        R2[((q0 >> 1) + g2 * 2 + e) * 1024 + (i0 + il)] = pk;
      }
    } else {
      const unsigned int pk0 = pkf16(tile[w][il][g2 * 4 + 0], tile[w][il][g2 * 4 + 1]);
      const unsigned int pk1 = pkf16(tile[w][il][g2 * 4 + 2], tile[w][il][g2 * 4 + 3]);
      const int hpg = ((q0 - 256) >> 3) + (g2 >> 1);
      unsigned int* dst = Ct + (hpg * 1024 + (i0 + il)) * 4 + (g2 & 1) * 2;
      dst[0] = pk0; dst[1] = pk1;
    }
    __syncthreads();                           // rep boundary (race-free reuse of zsh/wsh)
  }
}

// ---------------- k2: pairwise decode (r11 core) ----------------
__global__ __launch_bounds__(256) void k2_pair(const unsigned int* __restrict__ R2,
    const unsigned int* __restrict__ Ct, const float* __restrict__ W2,
    const float* __restrict__ b2v, float* __restrict__ out) {
  __shared__ unsigned int Rl[128][32];     // 16 KiB
  __shared__ float part[4][32][65];        // 33.3 KiB
  __shared__ float partkv[4][64];          // 1 KiB
  __shared__ unsigned int MulS[128];       // 0.5 KiB
  const int t = threadIdx.x;
  const int lane = t & 63, w = t >> 6;
  const int li = lane >> 4, lj = lane & 15;
  const int i0 = blockIdx.x * 32, j0 = blockIdx.y * 64;

  if (t < 128) {
    const unsigned int s0 = (W2[2 * t]     > 0.f) ? 0x3C00u : 0xBC00u;
    const unsigned int s1 = (W2[2 * t + 1] > 0.f) ? 0x3C00u : 0xBC00u;
    MulS[t] = s0 | (s1 << 16);
  }
  __syncthreads();

  #pragma unroll 1
  for (int rep = 0; rep < K2_REP; ++rep) {     // DIAGNOSTIC rep
    // stage R: 4096 u32, 16 per thread (staging barrier serializes vs prev rep's combine)
    #pragma unroll
    for (int k = 0; k < 16; ++k) {
      const int n = k * 256 + t;
      Rl[n >> 5][n & 31] = R2[(n >> 5) * 1024 + i0 + (n & 31)];
    }
    __syncthreads();

    const int hbase = w * 8;
    float acc[4][4] = {}, acc2[4][4] = {};
    float kvacc[4] = {};

#define LOADC(BUF, MQ, G) do { \
    _Pragma("unroll") \
    for (int jj = 0; jj < 4; ++jj) \
      BUF[jj] = *(const uint4v*)(Ct + (((hbase + (G)) * 1024) + j0 + lj + 16 * jj) * 4); \
    MQ = *(const uint4v*)&MulS[(hbase + (G)) * 4]; \
  } while (0)

#define COMPG(BUF, MQ, G) do { \
    _Pragma("unroll") \
    for (int hp2 = 0; hp2 < 4; ++hp2) { \
      const int hp = (hbase + (G)) * 4 + hp2; \
      const uint4v ra0 = *(const uint4v*)&Rl[hp][li * 8]; \
      const uint4v ra1 = *(const uint4v*)&Rl[hp][li * 8 + 4]; \
      const unsigned int mu = MQ[hp2]; \
      _Pragma("unroll") \
      for (int jj = 0; jj < 4; ++jj) { \
        const unsigned int c = BUF[jj][hp2]; \
        dot2acc(c, mu, kvacc[jj]); \
        _Pragma("unroll") \
        for (int ii = 0; ii < 4; ++ii) pkmaxdot(ra0[ii], c, mu, acc[ii][jj]); \
        _Pragma("unroll") \
        for (int ii = 0; ii < 4; ++ii) pkmaxdot(ra1[ii], c, mu, acc2[ii][jj]); \
      } \
    } \
  } while (0)

    {
      uint4v A[4], B[4], C[4];
      uint4v MA, MB, MC;
      LOADC(A, MA, 0); LOADC(B, MB, 1); LOADC(C, MC, 2);
      COMPG(A, MA, 0); LOADC(A, MA, 3);
      COMPG(B, MB, 1); LOADC(B, MB, 4);
      COMPG(C, MC, 2); LOADC(C, MC, 5);
      COMPG(A, MA, 3); LOADC(A, MA, 6);
      COMPG(B, MB, 4); LOADC(B, MB, 7);
      COMPG(C, MC, 5);
      COMPG(A, MA, 6);
      COMPG(B, MB, 7);
    }
#undef LOADC
#undef COMPG

    #pragma unroll
    for (int ii = 0; ii < 4; ++ii)
      #pragma unroll
      for (int jj = 0; jj < 4; ++jj) {
        part[w][li * 8 + ii][lj + 16 * jj]     = acc[ii][jj];
        part[w][li * 8 + 4 + ii][lj + 16 * jj] = acc2[ii][jj];
      }
    if (li == 0) {
      #pragma unroll
      for (int jj = 0; jj < 4; ++jj) partkv[w][lj + 16 * jj] = kvacc[jj];
    }
    __syncthreads();

    // combine + sigmoid: 256 threads x 8 outputs
    const int jl = t & 63, ib = (t >> 6) * 8;
    const float kvt = partkv[0][jl] + partkv[1][jl] + partkv[2][jl] + partkv[3][jl];
    const float base = b2v[0] - kvt;
    #pragma unroll
    for (int u = 0; u < 8; ++u) {
      const int il = ib + u;
      const float x = part[0][il][jl] + part[1][il][jl] +
                      part[2][il][jl] + part[3][il][jl] + base;
      out[(i0 + il) * NN + j0 + jl] = 1.f / (1.f + __expf(-x));
    }
  }
}

extern "C" void kernel_launch(void* const* d_in, const int* in_sizes, int n_in,
                              void* d_out, int out_size, void* d_ws, size_t ws_size,
                              hipStream_t stream) {
  const float* z  = (const float*)d_in[0];
  const float* W1 = (const float*)d_in[1];
  const float* b1 = (const float*)d_in[2];
  const float* W2 = (const float*)d_in[3];
  const float* b2 = (const float*)d_in[4];
  float* out = (float*)d_out;
  char* ws = (char*)d_ws;

  k1_fused<<<dim3(64, 8), 256, 0, stream>>>(z, W1, b1, W2, ws);
  k2_pair<<<dim3(32, 16), 256, 0, stream>>>(
      (const unsigned int*)(ws + R2_OFF), (const unsigned int*)(ws + CT_OFF),
      W2, b2, out);
}

// Round 15
// 26.176 us; speedup vs baseline: 3.1429x; 3.1429x over previous
//
#include <hip/hip_runtime.h>

#define NN 1024

typedef __attribute__((ext_vector_type(8))) short short8;
typedef __attribute__((ext_vector_type(4))) float floatx4;
typedef __attribute__((ext_vector_type(4))) unsigned int uint4v;
typedef _Float16 half2v __attribute__((ext_vector_type(2)));

// ---- ws layout (bytes) ----
#define R2_OFF   0u          // u32 R2[128][1024]: pk-f16 (R~_{2hp}, R~_{2hp+1}) per i
#define CT_OFF   524288u     // u32 Ct[32][1024][4]: pk-f16 Cn pairs, [hpg][j][hp&3]

__device__ __forceinline__ unsigned short f2bf(float x) {  // RNE f32->bf16
  unsigned u = __float_as_uint(x);
  return (unsigned short)((u + 0x7FFFu + ((u >> 16) & 1u)) >> 16);
}

__device__ __forceinline__ unsigned int pkf16(float a, float b) {
  unsigned int lo = (unsigned int)__builtin_bit_cast(unsigned short, (_Float16)a);
  unsigned int hi = (unsigned int)__builtin_bit_cast(unsigned short, (_Float16)b);
  return lo | (hi << 16);
}

__device__ __forceinline__ void dot2acc(unsigned int a, unsigned int b, float& acc) {
#if __has_builtin(__builtin_amdgcn_fdot2)
  acc = __builtin_amdgcn_fdot2(__builtin_bit_cast(half2v, a),
                               __builtin_bit_cast(half2v, b), acc, false);
#else
  asm("v_dot2_f32_f16 %0, %1, %2, %0" : "+v"(acc) : "v"(a), "v"(b));
#endif
}

// core: acc += dot2( pk_max(r, c), mul )
__device__ __forceinline__ void pkmaxdot(unsigned int r, unsigned int c,
                                         unsigned int mul, float& acc) {
  unsigned int m;
  asm("v_pk_max_f16 %0, %1, %2" : "=v"(m) : "v"(r), "v"(c));
  dot2acc(m, mul, acc);
}

// ---------------- k1: fused prep + fc1 GEMM (bf16 MFMA) -> pk-f16 R2 / Ct ----------------
// (byte-identical to r11 -- measured ~1.9 us in r14 diagnostic)
__global__ __launch_bounds__(256) void k1_fused(const float* __restrict__ z,
    const float* __restrict__ W1, const float* __restrict__ b1,
    const float* __restrict__ W2, char* __restrict__ ws) {
  __shared__ unsigned short zsh[16][272];      // 8.7 KB
  __shared__ unsigned short wsh[4][16][272];   // 34.8 KB
  __shared__ float tile[4][16][17];            // 4.4 KB
  unsigned int* R2 = (unsigned int*)(ws + R2_OFF);
  unsigned int* Ct = (unsigned int*)(ws + CT_OFF);

  const int t = threadIdx.x;
  const int l = t & 63, w = t >> 6;
  const int i0 = blockIdx.x * 16;
  const int tid = blockIdx.y * 4 + w;          // q-tile id 0..31
  const int q0 = tid * 16;                     // 0..496
  const bool topR = q0 < 256;
  const int h0 = q0 & 255;
  const int off = topR ? 0 : 256;

  // stage z i-tile: 1024 float4, 4 per thread, coalesced; convert to bf16
  #pragma unroll
  for (int k = 0; k < 4; ++k) {
    const int f = t + k * 256;                 // float4 index 0..1023
    const int r = f >> 6, c4 = f & 63;
    const float4 v = *(const float4*)(z + (i0 + r) * 256 + c4 * 4);
    ushort4 u;
    u.x = f2bf(v.x); u.y = f2bf(v.y); u.z = f2bf(v.z); u.w = f2bf(v.w);
    *(ushort4*)&zsh[r][c4 * 4] = u;
  }
  // stage W1 q-slice (per wave): row r, lane l reads float4 #l of the 256-f32 row
  #pragma unroll 4
  for (int r = 0; r < 16; ++r) {
    const int h = h0 + r;
    const float wa = fabsf(W2[h]);             // wave-uniform -> scalar
    const float sc = topR ? wa : -wa;          // C-half carries the negation
    const float4 v = *(const float4*)(W1 + h * 512 + off + l * 4);
    ushort4 u;
    u.x = f2bf(v.x * sc); u.y = f2bf(v.y * sc);
    u.z = f2bf(v.z * sc); u.w = f2bf(v.w * sc);
    *(ushort4*)&wsh[w][r][l * 4] = u;
  }
  __syncthreads();

  // MFMA: A = zsh rows (i), B = wsh rows (q)
  floatx4 acc = {0.f, 0.f, 0.f, 0.f};
  const int fr = l & 15, fg = (l >> 4) * 8;
  #pragma unroll
  for (int kk = 0; kk < 8; ++kk) {
    const short8 a  = *(const short8*)&zsh[fr][fg + kk * 32];
    const short8 bb = *(const short8*)&wsh[w][fr][fg + kk * 32];
    acc = __builtin_amdgcn_mfma_f32_16x16x32_bf16(a, bb, acc, 0, 0, 0);
  }

  const int col = l & 15, r0 = (l >> 4) * 4;   // D: col=lane&15, row=(lane>>4)*4+reg
  float bias = 0.f;
  if (topR) {                                  // R-half: fold |w2|*b1
    const int h = q0 + col;
    bias = b1[h] * fabsf(W2[h]);
  }
  #pragma unroll
  for (int q = 0; q < 4; ++q) tile[w][r0 + q][col] = acc[q] + bias;
  __syncthreads();
  const int il = l & 15, g2 = l >> 4;          // g2 in 0..3
  if (topR) {
    #pragma unroll
    for (int e = 0; e < 2; ++e) {
      const int qc = g2 * 4 + e * 2;
      const unsigned int pk = pkf16(tile[w][il][qc], tile[w][il][qc + 1]);
      R2[((q0 >> 1) + g2 * 2 + e) * 1024 + (i0 + il)] = pk;
    }
  } else {
    const unsigned int pk0 = pkf16(tile[w][il][g2 * 4 + 0], tile[w][il][g2 * 4 + 1]);
    const unsigned int pk1 = pkf16(tile[w][il][g2 * 4 + 2], tile[w][il][g2 * 4 + 3]);
    const int hpg = ((q0 - 256) >> 3) + (g2 >> 1);
    unsigned int* dst = Ct + (hpg * 1024 + (i0 + il)) * 4 + (g2 & 1) * 2;
    dst[0] = pk0; dst[1] = pk1;
  }
}

// ---------------- k2: pairwise decode, i-split waves, shared LDS-R, no combine ----------------
// grid (64,16) = 1024 blocks (4 blocks/CU), 256 thr = 4 waves (4 waves/SIMD, 2x r11).
// Wave w owns i-rows [i0+4w, i0+4w+4) for ALL 128 hp; lane = j. Accumulators fully
// lane-private: no part[]/partkv/combine (r14 counters: 33KB part[] LDS capped us at
// 2 waves/SIMD -> VALUBusy 46%). LDS = Rl (8KB, shared across waves) + MulS (0.5KB).
// Per hp: 1 broadcast ds_read_b128 (ra[4], uniform addr = free) + coalesced C load
// + 9 VALU (1 kv-dot2 + 4x{pk_max+dot2}). pk/dot VOP3P = 4 cyc (r14 measurement).
__global__ __launch_bounds__(256) void k2_pair(const unsigned int* __restrict__ R2,
    const unsigned int* __restrict__ Ct, const float* __restrict__ W2,
    const float* __restrict__ b2v, float* __restrict__ out) {
  __shared__ unsigned int Rl[128][16];     // 8 KiB
  __shared__ unsigned int MulS[128];       // 0.5 KiB
  const int t = threadIdx.x;
  const int lane = t & 63, w = t >> 6;
  const int i0 = blockIdx.x * 16, j0 = blockIdx.y * 64;
  const int j = j0 + lane;

  if (t < 128) {
    const unsigned int s0 = (W2[2 * t]     > 0.f) ? 0x3C00u : 0xBC00u;
    const unsigned int s1 = (W2[2 * t + 1] > 0.f) ? 0x3C00u : 0xBC00u;
    MulS[t] = s0 | (s1 << 16);
  }
  // stage Rl: 2048 u32, 8 per thread, coalesced in 16-lane groups
  #pragma unroll
  for (int k = 0; k < 8; ++k) {
    const int n = k * 256 + t;
    Rl[n >> 4][n & 15] = R2[(n >> 4) * 1024 + i0 + (n & 15)];
  }
  __syncthreads();

  const int iw = w * 4;                    // this wave's first i (Rl column)
  float acc0 = 0.f, acc1 = 0.f, acc2 = 0.f, acc3 = 0.f, kv = 0.f;

  // 2-deep software pipeline over 32 hpgs; C load coalesced (lane j contiguous 16B)
  uint4v cc = *(const uint4v*)(Ct + j * 4);              // hpg 0
  uint4v cn;
  #pragma unroll 2
  for (int g = 0; g < 32; ++g) {
    if (g < 31) cn = *(const uint4v*)(Ct + ((g + 1) * 1024 + j) * 4);
    const uint4v mq = *(const uint4v*)&MulS[g * 4];      // broadcast
    #pragma unroll
    for (int p = 0; p < 4; ++p) {
      const uint4v ra = *(const uint4v*)&Rl[g * 4 + p][iw];  // uniform addr -> broadcast
      const unsigned int c = cc[p], mu = mq[p];
      dot2acc(c, mu, kv);
      pkmaxdot(ra[0], c, mu, acc0);
      pkmaxdot(ra[1], c, mu, acc1);
      pkmaxdot(ra[2], c, mu, acc2);
      pkmaxdot(ra[3], c, mu, acc3);
    }
    cc = cn;
  }

  const float base = b2v[0] - kv;          // Kv[j] = b2 - sum_h s*Cn
  out[(i0 + iw + 0) * NN + j] = 1.f / (1.f + __expf(-(acc0 + base)));
  out[(i0 + iw + 1) * NN + j] = 1.f / (1.f + __expf(-(acc1 + base)));
  out[(i0 + iw + 2) * NN + j] = 1.f / (1.f + __expf(-(acc2 + base)));
  out[(i0 + iw + 3) * NN + j] = 1.f / (1.f + __expf(-(acc3 + base)));
}

extern "C" void kernel_launch(void* const* d_in, const int* in_sizes, int n_in,
                              void* d_out, int out_size, void* d_ws, size_t ws_size,
                              hipStream_t stream) {
  const float* z  = (const float*)d_in[0];
  const float* W1 = (const float*)d_in[1];
  const float* b1 = (const float*)d_in[2];
  const float* W2 = (const float*)d_in[3];
  const float* b2 = (const float*)d_in[4];
  float* out = (float*)d_out;
  char* ws = (char*)d_ws;

  k1_fused<<<dim3(64, 8), 256, 0, stream>>>(z, W1, b1, W2, ws);
  k2_pair<<<dim3(64, 16), 256, 0, stream>>>(
      (const unsigned int*)(ws + R2_OFF), (const unsigned int*)(ws + CT_OFF),
      W2, b2, out);
}